// Round 1
// baseline (667.523 us; speedup 1.0000x reference)
//
#include <hip/hip_runtime.h>
#include <math.h>

#define NUM_GRAPHS 4096
#define EMB 128

typedef float v4f __attribute__((ext_vector_type(4)));

#define LD4(p) (*(const v4f*)(p))

// One wave per graph (4096 waves = 1024 blocks x 4 waves, 4 blocks/CU).
// Each wave: binary-search its graph's row range in batch[], stream the rows
// with a 3-stage register pipeline (4 rows / 2 KB per stage), one-pass
// exp-weighted accumulation (no max-shift: |score| <~ 17 << 88, fminf guard),
// in-register cross-lane reduce, direct store. No workspace, no atomics.
__global__ __launch_bounds__(256) void att_pool_fused(
    const float* __restrict__ x, const int* __restrict__ batch,
    const float* __restrict__ w, float* __restrict__ out, const int n) {
  const int lane = threadIdx.x & 63;
  const int g    = (blockIdx.x * 256 + threadIdx.x) >> 6;   // graph id
  const int q    = lane >> 4;    // row-within-group (0..3)
  const int sl   = lane & 15;    // dim group: floats [4sl..4sl+3] and [64+4sl..]

  const v4f wa = LD4(w + 4 * sl);
  const v4f wb = LD4(w + 64 + 4 * sl);

  // Row range [s, e) of graph g: lower_bound(g), lower_bound(g+1).
  // Wave-uniform, ~40 L2/L3-cached probes.
  int lo = 0, hi = n;
  while (lo < hi) { const int m = (lo + hi) >> 1; if (batch[m] < g) lo = m + 1; else hi = m; }
  const int s = lo;
  hi = n;
  while (lo < hi) { const int m = (lo + hi) >> 1; if (batch[m] <= g) lo = m + 1; else hi = m; }
  const int e = lo;

  v4f acc0 = (v4f)0.f, acc1 = (v4f)0.f;
  float lacc = 0.f;

#define COMP(V0, V1)                                                          \
  do {                                                                        \
    float pa = V0.x * wa.x + V0.y * wa.y + V0.z * wa.z + V0.w * wa.w;         \
    float pb = V1.x * wb.x + V1.y * wb.y + V1.z * wb.z + V1.w * wb.w;         \
    float p = pa + pb;                                                        \
    p += __shfl_xor(p, 8, 64);                                                \
    p += __shfl_xor(p, 4, 64);                                                \
    p += __shfl_xor(p, 2, 64);                                                \
    p += __shfl_xor(p, 1, 64);                                                \
    const float ev = __expf(fminf(p, 80.f));                                  \
    acc0 += ev * V0; acc1 += ev * V1; lacc += ev;                             \
  } while (0)

  const int rows   = e - s;
  const int groups = rows >> 2;                 // full 4-row groups
  const float* xp  = x + (size_t)(s + q) * EMB + 4 * sl;

  if (groups >= 3) {
    // 3-deep rotating prefetch: >= 3 groups (6 KB/wave) in flight at all times.
    v4f A0 = LD4(xp),        A1 = LD4(xp + 64);
    v4f B0 = LD4(xp + 512),  B1 = LD4(xp + 576);
    v4f C0 = LD4(xp + 1024), C1 = LD4(xp + 1088);
    xp += 1536;
    int t = 0;
    for (; t + 5 < groups; t += 3) {
      COMP(A0, A1); A0 = LD4(xp); A1 = LD4(xp + 64); xp += 512;
      COMP(B0, B1); B0 = LD4(xp); B1 = LD4(xp + 64); xp += 512;
      COMP(C0, C1); C0 = LD4(xp); C1 = LD4(xp + 64); xp += 512;
    }
    const int rem = groups - t;                 // 3, 4, or 5
    COMP(A0, A1);
    if (rem > 3) { A0 = LD4(xp); A1 = LD4(xp + 64); xp += 512; }
    COMP(B0, B1);
    if (rem > 4) { B0 = LD4(xp); B1 = LD4(xp + 64); xp += 512; }
    COMP(C0, C1);
    if (rem > 3) COMP(A0, A1);
    if (rem > 4) COMP(B0, B1);
  } else {
    for (int t = 0; t < groups; ++t) {
      const v4f V0 = LD4(xp), V1 = LD4(xp + 64);
      xp += 512;
      COMP(V0, V1);
    }
  }

  const int tail = rows & 3;                    // 1..3 leftover rows
  if (tail) {
    const int row  = s + (groups << 2) + q;
    const int srow = (row < n) ? row : (n - 1);
    const float* tp = x + (size_t)srow * EMB + 4 * sl;
    const v4f V0 = LD4(tp), V1 = LD4(tp + 64);
    float pa = V0.x * wa.x + V0.y * wa.y + V0.z * wa.z + V0.w * wa.w;
    float pb = V1.x * wb.x + V1.y * wb.y + V1.z * wb.z + V1.w * wb.w;
    float p = pa + pb;
    p += __shfl_xor(p, 8, 64);
    p += __shfl_xor(p, 4, 64);
    p += __shfl_xor(p, 2, 64);
    p += __shfl_xor(p, 1, 64);
    const float ev = (row < e) ? __expf(fminf(p, 80.f)) : 0.f;
    acc0 += ev * V0; acc1 += ev * V1; lacc += ev;
  }
#undef COMP

  // Combine the 4 q-quarters (same graph by construction): xor 16, xor 32.
  #pragma unroll
  for (int m = 16; m <= 32; m <<= 1) {
    acc0.x += __shfl_xor(acc0.x, m, 64);
    acc0.y += __shfl_xor(acc0.y, m, 64);
    acc0.z += __shfl_xor(acc0.z, m, 64);
    acc0.w += __shfl_xor(acc0.w, m, 64);
    acc1.x += __shfl_xor(acc1.x, m, 64);
    acc1.y += __shfl_xor(acc1.y, m, 64);
    acc1.z += __shfl_xor(acc1.z, m, 64);
    acc1.w += __shfl_xor(acc1.w, m, 64);
    lacc   += __shfl_xor(lacc,   m, 64);
  }

  if (q == 0) {                                 // lanes 0..15 write graph g
    const float inv = 1.f / (fmaxf(lacc, 1e-30f) * (float)((rows > 0) ? rows : 1));
    float* d = out + (size_t)g * EMB + 4 * sl;
    *(v4f*)d        = acc0 * inv;
    *(v4f*)(d + 64) = acc1 * inv;
  }
  if (g == 0) {                                 // att_weight passthrough
    out[NUM_GRAPHS * EMB + lane]      = w[lane];
    out[NUM_GRAPHS * EMB + 64 + lane] = w[64 + lane];
  }
}

extern "C" void kernel_launch(void* const* d_in, const int* in_sizes, int n_in,
                              void* d_out, int out_size, void* d_ws, size_t ws_size,
                              hipStream_t stream) {
  const float* x     = (const float*)d_in[0];
  const int*   batch = (const int*)d_in[1];
  const float* w     = (const float*)d_in[2];
  const int n = in_sizes[0] / EMB;   // 1,000,000 nodes

  att_pool_fused<<<NUM_GRAPHS / 4, 256, 0, stream>>>(x, batch, w, (float*)d_out, n);
}

// Round 2
// 632.644 us; speedup vs baseline: 1.0551x; 1.0551x over previous
//
#include <hip/hip_runtime.h>
#include <math.h>

#define NUM_GRAPHS 4096
#define EMB 128
#define NWAVES 8192     // 2048 blocks x 4 waves: 8 blocks/CU (needs <=64 VGPR)

typedef float v4f __attribute__((ext_vector_type(4)));

// ws layout (floats): [wsum: G*128][denom: G][start: G+1 ints]
#define WSUM_OFF   0
#define DENOM_OFF  (NUM_GRAPHS * EMB)
#define START_OFF  (NUM_GRAPHS * EMB + NUM_GRAPHS)
#define ZERO_COUNT (NUM_GRAPHS * EMB + NUM_GRAPHS)

// Zero accumulators and build start[] (start[g] = first i with batch[i] >= g)
// via boundary scatter.
__global__ __launch_bounds__(256) void init_kernel(const int* __restrict__ batch, int n,
                                                   float* __restrict__ ws) {
    const int i = blockIdx.x * 256 + threadIdx.x;
    if (i < ZERO_COUNT) ws[i] = 0.f;
    int* start = (int*)(ws + START_OFF);
    if (i < n) {
        const int b1 = batch[i];
        const int b0 = (i == 0) ? -1 : batch[i - 1];
        for (int g = b0 + 1; g <= b1; ++g) start[g] = i;
        if (i == n - 1)
            for (int g = b1 + 1; g <= NUM_GRAPHS; ++g) start[g] = n;
    }
}

// Statically balanced: wave wid owns nodes [wid*n/W, (wid+1)*n/W) — equal bytes
// per wave. 8 blocks/CU (32 waves/CU) for max memory-level parallelism; the
// 2-deep rotating prefetch keeps 2 loads (2 KB) in flight per wave while
// holding VGPR <= 64 so all 8 waves/SIMD are resident.
// 4 nodes/iteration (quarter-wave per node): lane = q*16+s; node i+q,
// dims [4s..4s+3] and [64+4s..]. Score reduce intra-16 (masks 8,4,2,1).
// No max-shift needed (|score| <~ 17 << 88; fminf guard). Atomic flush only
// at graph-run ends.
__global__ __launch_bounds__(256, 8) void pool_kernel(const float* __restrict__ x,
                                                      const float* __restrict__ w,
                                                      const int* __restrict__ batch,
                                                      float* __restrict__ ws, int n) {
    const int lane = threadIdx.x & 63;
    const int wid  = (blockIdx.x * 256 + threadIdx.x) >> 6;
    const int q    = lane >> 4;    // node offset within 4-node group
    const int s    = lane & 15;    // dim group
    const int s0 = (int)((long long)wid * n / NWAVES);
    const int s1 = (int)((long long)(wid + 1) * n / NWAVES);
    if (s0 >= s1) return;

    float* __restrict__ wsum  = ws + WSUM_OFF;
    float* __restrict__ denom = ws + DENOM_OFF;
    const int* __restrict__ start = (const int*)(ws + START_OFF);

    const v4f wa = *(const v4f*)(w + 4 * s);
    const v4f wb = *(const v4f*)(w + 64 + 4 * s);

#define COMP(V0, V1)                                                          \
    do {                                                                      \
        float p = V0.x * wa.x + V0.y * wa.y + V0.z * wa.z + V0.w * wa.w       \
                + V1.x * wb.x + V1.y * wb.y + V1.z * wb.z + V1.w * wb.w;      \
        p += __shfl_xor(p, 8, 64);                                            \
        p += __shfl_xor(p, 4, 64);                                            \
        p += __shfl_xor(p, 2, 64);                                            \
        p += __shfl_xor(p, 1, 64);                                            \
        const float e = __expf(fminf(p, 80.f));                               \
        acc0 += e * V0; acc1 += e * V1; lacc += e;                            \
    } while (0)

    int g = batch[s0];
    int i = s0;
    while (i < s1) {
        while (start[g + 1] <= i) ++g;            // wave-uniform, ~1 probe per run
        const int rend = min(s1, start[g + 1]);
        v4f acc0 = (v4f)0.f, acc1 = (v4f)0.f;
        float lacc = 0.f;

        const int nfull = (rend - i) & ~3;        // rows in full 4-node groups
        if (nfull) {
            const float* xp = x + (size_t)(i + q) * EMB + 4 * s;
            v4f A0 = __builtin_nontemporal_load((const v4f*)xp);
            v4f A1 = __builtin_nontemporal_load((const v4f*)(xp + 64));
            xp += 512;
            for (int t = 4; t < nfull; t += 4) {
                const v4f B0 = __builtin_nontemporal_load((const v4f*)xp);
                const v4f B1 = __builtin_nontemporal_load((const v4f*)(xp + 64));
                xp += 512;
                COMP(A0, A1);                     // waits vmcnt(2): B in flight
                A0 = B0; A1 = B1;
            }
            COMP(A0, A1);
            i += nfull;
        }
        if (i < rend) {                           // 1..3 tail nodes of this run
            const int row  = i + q;
            const int srow = min(row, n - 1);
            const float* xp = x + (size_t)srow * EMB + 4 * s;
            const v4f v0 = __builtin_nontemporal_load((const v4f*)xp);
            const v4f v1 = __builtin_nontemporal_load((const v4f*)(xp + 64));
            float p = v0.x * wa.x + v0.y * wa.y + v0.z * wa.z + v0.w * wa.w
                    + v1.x * wb.x + v1.y * wb.y + v1.z * wb.z + v1.w * wb.w;
            p += __shfl_xor(p, 8, 64);
            p += __shfl_xor(p, 4, 64);
            p += __shfl_xor(p, 2, 64);
            p += __shfl_xor(p, 1, 64);
            const float e = (row < rend) ? __expf(fminf(p, 80.f)) : 0.f;
            acc0 += e * v0;
            acc1 += e * v1;
            lacc += e;
            i = rend;
        }

        // combine the 4 quarters (same graph by construction): xor 16, xor 32
        #pragma unroll
        for (int m = 16; m <= 32; m <<= 1) {
            acc0.x += __shfl_xor(acc0.x, m, 64);
            acc0.y += __shfl_xor(acc0.y, m, 64);
            acc0.z += __shfl_xor(acc0.z, m, 64);
            acc0.w += __shfl_xor(acc0.w, m, 64);
            acc1.x += __shfl_xor(acc1.x, m, 64);
            acc1.y += __shfl_xor(acc1.y, m, 64);
            acc1.z += __shfl_xor(acc1.z, m, 64);
            acc1.w += __shfl_xor(acc1.w, m, 64);
            lacc   += __shfl_xor(lacc,   m, 64);
        }
        if (q == 0) {                              // lanes 0..15 flush
            float* d0 = wsum + (size_t)g * EMB + 4 * s;
            atomicAdd(d0 + 0,  acc0.x);
            atomicAdd(d0 + 1,  acc0.y);
            atomicAdd(d0 + 2,  acc0.z);
            atomicAdd(d0 + 3,  acc0.w);
            atomicAdd(d0 + 64, acc1.x);
            atomicAdd(d0 + 65, acc1.y);
            atomicAdd(d0 + 66, acc1.z);
            atomicAdd(d0 + 67, acc1.w);
            if (s == 0) atomicAdd(denom + g, lacc);
        }
    }
#undef COMP
}

__global__ __launch_bounds__(256) void finalize_kernel(const float* __restrict__ ws,
                                                       const float* __restrict__ w,
                                                       float* __restrict__ out) {
    const int tid = blockIdx.x * 256 + threadIdx.x;
    const float* wsum  = ws + WSUM_OFF;
    const float* denom = ws + DENOM_OFF;
    const int* start   = (const int*)(ws + START_OFF);
    if (tid < NUM_GRAPHS * EMB) {
        const int g = tid >> 7;
        const int cnt = start[g + 1] - start[g];
        const float d = fmaxf(denom[g], 1e-30f);
        out[tid] = wsum[tid] / (d * (float)max(cnt, 1));
    }
    if (tid < EMB) out[NUM_GRAPHS * EMB + tid] = w[tid];
}

extern "C" void kernel_launch(void* const* d_in, const int* in_sizes, int n_in,
                              void* d_out, int out_size, void* d_ws, size_t ws_size,
                              hipStream_t stream) {
    const float* x     = (const float*)d_in[0];
    const int*   batch = (const int*)d_in[1];
    const float* w     = (const float*)d_in[2];
    float* out = (float*)d_out;
    float* ws  = (float*)d_ws;
    const int n = in_sizes[0] / EMB;   // 1,000,000 nodes

    const int init_blocks = (n + 255) / 256;                 // covers ZERO_COUNT too
    init_kernel<<<init_blocks, 256, 0, stream>>>(batch, n, ws);

    pool_kernel<<<NWAVES / 4, 256, 0, stream>>>(x, w, batch, ws, n);

    finalize_kernel<<<(NUM_GRAPHS * EMB + 255) / 256, 256, 0, stream>>>(ws, w, out);
}

// Round 3
// 628.838 us; speedup vs baseline: 1.0615x; 1.0061x over previous
//
#include <hip/hip_runtime.h>
#include <math.h>

#define NUM_GRAPHS 4096
#define EMB 128
#define NWAVES 4096     // 1024 blocks x 4 waves: 4 blocks/CU, statically balanced

typedef float v4f __attribute__((ext_vector_type(4)));

// ws layout (floats): [wsum: G*128][denom: G][start: G+1 ints]
#define WSUM_OFF   0
#define DENOM_OFF  (NUM_GRAPHS * EMB)
#define START_OFF  (NUM_GRAPHS * EMB + NUM_GRAPHS)
#define ZERO_COUNT (NUM_GRAPHS * EMB + NUM_GRAPHS)

// Intra-16 all-reduce sum via DPP (pure VALU, no ds_bpermute / lgkmcnt):
//   step1 quad_perm [1,0,3,2] = xor1   (0xB1)
//   step2 quad_perm [2,3,0,1] = xor2   (0x4E)
//   step3 row_ror:4                     (0x124)  adds neighbor quad
//   step4 row_ror:8  (== xor8 in row16) (0x128)  adds the far pair
// After 4 steps every lane of the 16-group holds the full 16-lane sum.
#define DPP_RADD(p, ctrl)                                                     \
    (p) += __int_as_float(__builtin_amdgcn_update_dpp(                        \
        0, __float_as_int(p), (ctrl), 0xf, 0xf, true))

// Zero accumulators and build start[] (start[g] = first i with batch[i] >= g)
// via boundary scatter.
__global__ __launch_bounds__(256) void init_kernel(const int* __restrict__ batch, int n,
                                                   float* __restrict__ ws) {
    const int i = blockIdx.x * 256 + threadIdx.x;
    if (i < ZERO_COUNT) ws[i] = 0.f;
    int* start = (int*)(ws + START_OFF);
    if (i < n) {
        const int b1 = batch[i];
        const int b0 = (i == 0) ? -1 : batch[i - 1];
        for (int g = b0 + 1; g <= b1; ++g) start[g] = i;
        if (i == n - 1)
            for (int g = b1 + 1; g <= NUM_GRAPHS; ++g) start[g] = n;
    }
}

// Statically balanced: wave wid owns nodes [wid*n/W, (wid+1)*n/W) — equal bytes
// per wave, 4 identical blocks per CU -> no dispatch tail. 4 nodes/iteration
// (quarter-wave per node): lane = q*16+s; node i+q, dims [4s..4s+3] and
// [64+4s..]. Score reduce intra-16 via DPP butterfly (no LDS-pipe traffic).
// No max-shift needed (|score| <~ 17 << 88; fminf guard). Atomic flush only
// at graph-run ends.
__global__ __launch_bounds__(256) void pool_kernel(const float* __restrict__ x,
                                                   const float* __restrict__ w,
                                                   const int* __restrict__ batch,
                                                   float* __restrict__ ws, int n) {
    const int lane = threadIdx.x & 63;
    const int wid  = (blockIdx.x * 256 + threadIdx.x) >> 6;
    const int q    = lane >> 4;    // node offset within 4-node group
    const int s    = lane & 15;    // dim group
    const int s0 = (int)((long long)wid * n / NWAVES);
    const int s1 = (int)((long long)(wid + 1) * n / NWAVES);
    if (s0 >= s1) return;

    float* __restrict__ wsum  = ws + WSUM_OFF;
    float* __restrict__ denom = ws + DENOM_OFF;
    const int* __restrict__ start = (const int*)(ws + START_OFF);

    const v4f wa = *(const v4f*)(w + 4 * s);
    const v4f wb = *(const v4f*)(w + 64 + 4 * s);

    int g = batch[s0];
    int i = s0;
    while (i < s1) {
        while (start[g + 1] <= i) ++g;            // wave-uniform, ~1 probe per run
        const int rend = min(s1, start[g + 1]);
        v4f acc0 = (v4f)0.f, acc1 = (v4f)0.f;
        float lacc = 0.f;

        #pragma unroll 4
        for (; i + 4 <= rend; i += 4) {
            const float* xp = x + (size_t)(i + q) * EMB + 4 * s;
            const v4f v0 = __builtin_nontemporal_load((const v4f*)xp);
            const v4f v1 = __builtin_nontemporal_load((const v4f*)(xp + 64));
            float p = v0.x * wa.x + v0.y * wa.y + v0.z * wa.z + v0.w * wa.w
                    + v1.x * wb.x + v1.y * wb.y + v1.z * wb.z + v1.w * wb.w;
            DPP_RADD(p, 0xB1);
            DPP_RADD(p, 0x4E);
            DPP_RADD(p, 0x124);
            DPP_RADD(p, 0x128);
            const float e = __expf(fminf(p, 80.f));
            acc0 += e * v0;
            acc1 += e * v1;
            lacc += e;
        }
        if (i < rend) {                            // 1..3 tail nodes of this run
            const int row  = i + q;
            const int srow = min(row, n - 1);
            const float* xp = x + (size_t)srow * EMB + 4 * s;
            const v4f v0 = __builtin_nontemporal_load((const v4f*)xp);
            const v4f v1 = __builtin_nontemporal_load((const v4f*)(xp + 64));
            float p = v0.x * wa.x + v0.y * wa.y + v0.z * wa.z + v0.w * wa.w
                    + v1.x * wb.x + v1.y * wb.y + v1.z * wb.z + v1.w * wb.w;
            DPP_RADD(p, 0xB1);
            DPP_RADD(p, 0x4E);
            DPP_RADD(p, 0x124);
            DPP_RADD(p, 0x128);
            const float e = (row < rend) ? __expf(fminf(p, 80.f)) : 0.f;
            acc0 += e * v0;
            acc1 += e * v1;
            lacc += e;
            i = rend;
        }

        // combine the 4 quarters (same graph by construction): xor 16, xor 32
        #pragma unroll
        for (int m = 16; m <= 32; m <<= 1) {
            acc0.x += __shfl_xor(acc0.x, m, 64);
            acc0.y += __shfl_xor(acc0.y, m, 64);
            acc0.z += __shfl_xor(acc0.z, m, 64);
            acc0.w += __shfl_xor(acc0.w, m, 64);
            acc1.x += __shfl_xor(acc1.x, m, 64);
            acc1.y += __shfl_xor(acc1.y, m, 64);
            acc1.z += __shfl_xor(acc1.z, m, 64);
            acc1.w += __shfl_xor(acc1.w, m, 64);
            lacc   += __shfl_xor(lacc,   m, 64);
        }
        if (q == 0) {                              // lanes 0..15 flush
            float* d0 = wsum + (size_t)g * EMB + 4 * s;
            atomicAdd(d0 + 0,  acc0.x);
            atomicAdd(d0 + 1,  acc0.y);
            atomicAdd(d0 + 2,  acc0.z);
            atomicAdd(d0 + 3,  acc0.w);
            atomicAdd(d0 + 64, acc1.x);
            atomicAdd(d0 + 65, acc1.y);
            atomicAdd(d0 + 66, acc1.z);
            atomicAdd(d0 + 67, acc1.w);
            if (s == 0) atomicAdd(denom + g, lacc);
        }
    }
}

__global__ __launch_bounds__(256) void finalize_kernel(const float* __restrict__ ws,
                                                       const float* __restrict__ w,
                                                       float* __restrict__ out) {
    const int tid = blockIdx.x * 256 + threadIdx.x;
    const float* wsum  = ws + WSUM_OFF;
    const float* denom = ws + DENOM_OFF;
    const int* start   = (const int*)(ws + START_OFF);
    if (tid < NUM_GRAPHS * EMB) {
        const int g = tid >> 7;
        const int cnt = start[g + 1] - start[g];
        const float d = fmaxf(denom[g], 1e-30f);
        out[tid] = wsum[tid] / (d * (float)max(cnt, 1));
    }
    if (tid < EMB) out[NUM_GRAPHS * EMB + tid] = w[tid];
}

extern "C" void kernel_launch(void* const* d_in, const int* in_sizes, int n_in,
                              void* d_out, int out_size, void* d_ws, size_t ws_size,
                              hipStream_t stream) {
    const float* x     = (const float*)d_in[0];
    const int*   batch = (const int*)d_in[1];
    const float* w     = (const float*)d_in[2];
    float* out = (float*)d_out;
    float* ws  = (float*)d_ws;
    const int n = in_sizes[0] / EMB;   // 1,000,000 nodes

    const int init_blocks = (n + 255) / 256;                 // covers ZERO_COUNT too
    init_kernel<<<init_blocks, 256, 0, stream>>>(batch, n, ws);

    pool_kernel<<<NWAVES / 4, 256, 0, stream>>>(x, w, batch, ws, n);

    finalize_kernel<<<(NUM_GRAPHS * EMB + 255) / 256, 256, 0, stream>>>(ws, w, out);
}